// Round 1
// 157.025 us; speedup vs baseline: 1.0240x; 1.0240x over previous
//
#include <hip/hip_runtime.h>

// Problem constants (from reference): B=16, L=512, D=512, T=4096, P=4
constexpr int Bn = 16;
constexpr int Ln = 512;
constexpr int Dn = 512;
constexpr int Tn = 4096;
constexpr int Pn = 4;

constexpr int D4       = Dn / 4;             // 128 float4 of encoder data per row
constexpr int ROW_F4   = (Dn + Pn) / 4;      // 129 float4 per output row
constexpr int NROWS    = Bn * Tn;            // 65536 output rows
constexpr int TOTAL_D4 = NROWS * D4;         // 8,388,608 float4 (D-part only)

constexpr int THREADS       = 256;
constexpr int F4_PER_THREAD = 4;                         // 4 independent chains/thread
constexpr int F4_PER_BLK    = THREADS * F4_PER_THREAD;   // 1024 f4 = exactly 8 rows
constexpr int NBLK          = TOTAL_D4 / F4_PER_BLK;     // 8192 blocks
constexpr int NXCD          = 8;
constexpr int BLK_PER_XCD   = NBLK / NXCD;               // 1024 = exactly 2 batches/XCD

// Kernel 1 (unchanged from verified version): per-batch inclusive cumsum
// (LDS Hillis-Steele) + per-frame binary search (searchsorted side="right").
// 4 blocks per batch; every idx_map entry written exactly once, coalesced.
// Frames >= cum[L-1] get -1 (D-part of output is zeros there).
__global__ __launch_bounds__(Ln) void cum_search_kernel(
    const int* __restrict__ durations, int* __restrict__ idx_map) {
    const int b     = blockIdx.x >> 2;   // batch
    const int chunk = blockIdx.x & 3;    // which 1024-frame chunk
    const int l     = threadIdx.x;       // 0..511

    __shared__ int cum[Ln];
    cum[l] = durations[b * Ln + l];
    __syncthreads();
    for (int off = 1; off < Ln; off <<= 1) {
        int v = (l >= off) ? cum[l - off] : 0;
        __syncthreads();
        cum[l] += v;
        __syncthreads();
    }
    const int total = cum[Ln - 1];

    #pragma unroll
    for (int f = 0; f < 2; ++f) {
        const int t = chunk * 1024 + f * Ln + l;
        int lo = 0, hi = Ln;
        while (lo < hi) {
            const int mid = (lo + hi) >> 1;
            if (cum[mid] <= t) lo = mid + 1; else hi = mid;
        }
        const int idx = (t < total) ? min(lo, Ln - 1) : -1;
        idx_map[b * Tn + t] = idx;
    }
}

// Kernel 2: expand restructured around the natural 128+1 row split.
//  - D-part iterated over B*T*128 f4: row = g>>7, c4 = g&127 — shifts only,
//    no magic-div by 129.
//  - Each wave's 64 consecutive g lie in one 128-f4 half-row => idx_map[row]
//    is WAVE-UNIFORM: the idx>=0 branch doesn't diverge, and zero-frames
//    (~56% of rows) skip the enc gather as a whole wave.
//  - Output f4 index = row*129 + c4 = g + row (one add).
//  - fpos (the 129th f4) handled by an 8-thread per-block tail: removes the
//    per-wave two-sided divergence the old c4==128 branch caused every
//    other wave.
//  - 4 f4/thread: all idx loads issued, then all enc loads, then all stores
//    (4 overlapped idx_map->enc4 dependency chains per thread).
//  - XCD swizzle kept: 1024 blocks/XCD = exactly 2 batches => that XCD's enc
//    slice (2.1 MB) stays resident in its private 4 MB L2.
__global__ __launch_bounds__(THREADS) void expand_kernel(
    const float4* __restrict__ enc4, const float4* __restrict__ fpos4,
    const int* __restrict__ idx_map, float4* __restrict__ out4) {
    const int xcd     = blockIdx.x & (NXCD - 1);
    const int j       = blockIdx.x >> 3;
    const int blk_lin = xcd * BLK_PER_XCD + j;        // swizzled linear block id
    const int base    = blk_lin * F4_PER_BLK + threadIdx.x;

    int row[F4_PER_THREAD], idx[F4_PER_THREAD];
    #pragma unroll
    for (int h = 0; h < F4_PER_THREAD; ++h) {
        row[h] = (base + h * THREADS) >> 7;           // D4 = 128
        idx[h] = idx_map[row[h]];                     // wave-uniform load
    }

    float4 v[F4_PER_THREAD];
    #pragma unroll
    for (int h = 0; h < F4_PER_THREAD; ++h) {
        const int g  = base + h * THREADS;
        const int c4 = g & (D4 - 1);
        const int b  = row[h] >> 12;                  // Tn = 4096 = 2^12
        v[h] = make_float4(0.f, 0.f, 0.f, 0.f);
        if (idx[h] >= 0) {                            // wave-uniform branch
            // enc f4 index: (b*Ln + idx) * D4 + c4
            v[h] = enc4[(((b << 9) + idx[h]) << 7) + c4];
        }
    }

    #pragma unroll
    for (int h = 0; h < F4_PER_THREAD; ++h) {
        const int g = base + h * THREADS;
        out4[g + row[h]] = v[h];                      // row*129 + c4
    }

    // fpos tail: this block owns rows r0..r0+7; 8 threads copy their fpos f4.
    if (threadIdx.x < 8) {
        const int r = blk_lin * 8 + threadIdx.x;
        out4[r * ROW_F4 + (ROW_F4 - 1)] = fpos4[r];
    }
}

extern "C" void kernel_launch(void* const* d_in, const int* in_sizes, int n_in,
                              void* d_out, int out_size, void* d_ws, size_t ws_size,
                              hipStream_t stream) {
    const float* enc  = (const float*)d_in[0];  // [B, L, D] f32
    const int*   dur  = (const int*)d_in[1];    // [B, L] i32
    const float* fpos = (const float*)d_in[2];  // [B, T, P] f32
    // d_in[3] = input_lengths, unused by the reference computation

    float* out = (float*)d_out;                 // [B, T, D+P] f32
    int* idx_map = (int*)d_ws;                  // [B, T] i32 = 256 KB scratch

    cum_search_kernel<<<Bn * 4, Ln, 0, stream>>>(dur, idx_map);

    static_assert(TOTAL_D4 % F4_PER_BLK == 0 && NBLK % NXCD == 0, "sizing");
    static_assert(F4_PER_BLK == 8 * D4, "block must cover exactly 8 rows");
    expand_kernel<<<NBLK, THREADS, 0, stream>>>(
        (const float4*)enc, (const float4*)fpos, idx_map, (float4*)out);
}